// Round 4
// baseline (4865.524 us; speedup 1.0000x reference)
//
#include <hip/hip_runtime.h>
#include <math.h>

#define B 32
#define S 256
#define H 768
#define V 30522
#define NU 5
#define MV 4
#define NEG_INF -10000.0f

// logits GEMM tiling
#define VP 30720      // padded V stride (120*256)
#define VTILES 120
#define VT 256        // v per block
#define KSPL 6
#define KCH 128       // 768/6
#define KT 16         // k per LDS phase
#define NPH (KCH/KT)  // 8 phases

__device__ __forceinline__ float sigm(float x){ return 1.0f/(1.0f + expf(-x)); }

// ---------------- GRU: h_new = GRUCell(w, h), writes h and h-transposed --------
__global__ __launch_bounds__(256) void gru_kernel(
    const float* __restrict__ wp, int wstride,
    const float* __restrict__ hin, float* __restrict__ hout,
    float* __restrict__ htr,
    const float* __restrict__ Wih, const float* __restrict__ Whh,
    const float* __restrict__ bih, const float* __restrict__ bhh)
{
    int wid  = blockIdx.x * 4 + (threadIdx.x >> 6);
    int lane = threadIdx.x & 63;
    int j  = wid >> 2;
    int bg = wid & 3;

    float aI0[8], aI1[8], aI2[8], aH0[8], aH1[8], aH2[8];
#pragma unroll
    for (int bb = 0; bb < 8; bb++){ aI0[bb]=aI1[bb]=aI2[bb]=aH0[bb]=aH1[bb]=aH2[bb]=0.f; }

#pragma unroll
    for (int it = 0; it < 3; it++){
        int k = it*256 + lane*4;
        float4 w0 = *(const float4*)(Wih + (size_t)(0*H + j)*H + k);
        float4 w1 = *(const float4*)(Wih + (size_t)(1*H + j)*H + k);
        float4 w2 = *(const float4*)(Wih + (size_t)(2*H + j)*H + k);
        float4 u0 = *(const float4*)(Whh + (size_t)(0*H + j)*H + k);
        float4 u1 = *(const float4*)(Whh + (size_t)(1*H + j)*H + k);
        float4 u2 = *(const float4*)(Whh + (size_t)(2*H + j)*H + k);
#pragma unroll
        for (int bb = 0; bb < 8; bb++){
            int b = bg*8 + bb;
            float4 x = *(const float4*)(wp  + (size_t)b*wstride + k);
            float4 h = *(const float4*)(hin + (size_t)b*H + k);
            aI0[bb] += w0.x*x.x + w0.y*x.y + w0.z*x.z + w0.w*x.w;
            aI1[bb] += w1.x*x.x + w1.y*x.y + w1.z*x.z + w1.w*x.w;
            aI2[bb] += w2.x*x.x + w2.y*x.y + w2.z*x.z + w2.w*x.w;
            aH0[bb] += u0.x*h.x + u0.y*h.y + u0.z*h.z + u0.w*h.w;
            aH1[bb] += u1.x*h.x + u1.y*h.y + u1.z*h.z + u1.w*h.w;
            aH2[bb] += u2.x*h.x + u2.y*h.y + u2.z*h.z + u2.w*h.w;
        }
    }
    float rRZ0[8], rRZ1[8], rIN[8], rHN[8];
#pragma unroll
    for (int bb = 0; bb < 8; bb++){
        rRZ0[bb] = aI0[bb] + aH0[bb];
        rRZ1[bb] = aI1[bb] + aH1[bb];
        rIN[bb]  = aI2[bb];
        rHN[bb]  = aH2[bb];
    }
#pragma unroll
    for (int bb = 0; bb < 8; bb++){
#pragma unroll
        for (int m = 32; m >= 1; m >>= 1){
            rRZ0[bb] += __shfl_xor(rRZ0[bb], m, 64);
            rRZ1[bb] += __shfl_xor(rRZ1[bb], m, 64);
            rIN[bb]  += __shfl_xor(rIN[bb],  m, 64);
            rHN[bb]  += __shfl_xor(rHN[bb],  m, 64);
        }
    }
    if (lane == 0){
        float brz0 = bih[j]     + bhh[j];
        float brz1 = bih[H+j]   + bhh[H+j];
        float bin_ = bih[2*H+j];
        float bhn_ = bhh[2*H+j];
#pragma unroll
        for (int bb = 0; bb < 8; bb++){
            int b = bg*8 + bb;
            float r = sigm(rRZ0[bb] + brz0);
            float z = sigm(rRZ1[bb] + brz1);
            float n = tanhf(rIN[bb] + bin_ + r*(rHN[bb] + bhn_));
            float ho = hin[(size_t)b*H + j];
            float hv = (1.0f - z)*n + z*ho;
            hout[(size_t)b*H + j] = hv;
            htr[(size_t)j*32 + b] = hv;
        }
    }
}

// ---------------- attn_e[b,s] = enc[b,s,:] . h[b,:] ----------------------------
__global__ __launch_bounds__(256) void attn_e_kernel(
    const float* __restrict__ hb, const float* __restrict__ enc,
    float* __restrict__ attnE)
{
    int wid  = blockIdx.x * 4 + (threadIdx.x >> 6);
    int lane = threadIdx.x & 63;
    int b = wid >> 8;
    int s = wid & 255;
    const float* er = enc + ((size_t)b*S + s)*H;
    const float* hr = hb + (size_t)b*H;
    float acc = 0.f;
#pragma unroll
    for (int it = 0; it < 3; it++){
        int k = it*256 + lane*4;
        float4 e4 = *(const float4*)(er + k);
        float4 h4 = *(const float4*)(hr + k);
        acc += e4.x*h4.x + e4.y*h4.y + e4.z*h4.z + e4.w*h4.w;
    }
#pragma unroll
    for (int m = 32; m >= 1; m >>= 1) acc += __shfl_xor(acc, m, 64);
    if (lane == 0) attnE[b*S + s] = acc;
}

// ------- masked softmax over S (redundant per k-chunk) + context chunk ---------
__global__ __launch_bounds__(256) void ctx_kernel(
    const float* __restrict__ attnE, const int* __restrict__ ids,
    const float* __restrict__ enc, float* __restrict__ attnH,
    float* __restrict__ ctx)
{
    __shared__ float ah[S];
    __shared__ float red[S];
    int b  = blockIdx.x / 3;
    int kc = blockIdx.x % 3;
    int t  = threadIdx.x;

    float e = attnE[b*S + t];
    if (ids[b*S + t] == 0) e = NEG_INF;
    red[t] = e; __syncthreads();
    for (int s = 128; s > 0; s >>= 1){ if (t < s) red[t] = fmaxf(red[t], red[t+s]); __syncthreads(); }
    float mx = red[0]; __syncthreads();
    float p = expf(e - mx);
    red[t] = p; __syncthreads();
    for (int s = 128; s > 0; s >>= 1){ if (t < s) red[t] += red[t+s]; __syncthreads(); }
    float a = p / red[0];
    ah[t] = a;
    if (kc == 0) attnH[b*S + t] = a;
    __syncthreads();

    int k = kc*256 + t;
    const float* ep = enc + (size_t)b*S*H + k;
    float acc = 0.f;
#pragma unroll 4
    for (int s = 0; s < S; s++) acc += ah[s] * ep[(size_t)s*H];
    ctx[b*H + k] = acc;
}

// ---------------- logits partial GEMM: 256v x 32b tile, K/6 per block ----------
// grid VTILES*KSPL+1: [0,720) = vt*KSPL + ks; block 720 = p_gen.
// Per k per lane: 1 conflict-free ds_read_b128 (E, 4v) + 2 broadcast b128 (h, 8b)
// + 32 FMA  -> 4 FLOP per LDS byte -> VALU-bound.
__global__ __launch_bounds__(256) void logits_kernel(
    const float* __restrict__ E, const float* __restrict__ htr,
    float* __restrict__ part,
    const float* __restrict__ hb, const float* __restrict__ wp, int wstride,
    const float* __restrict__ ctx, const float* __restrict__ wgw,
    const float* __restrict__ wgb, float* __restrict__ pgen)
{
    int t = threadIdx.x;

    if (blockIdx.x == VTILES*KSPL){
        int b = t >> 3, sl = t & 7;
        float s = 0.f;
        for (int i = sl; i < 2304; i += 8){
            float xv;
            if (i < 768)        xv = wp[(size_t)b*wstride + i];
            else if (i < 1536)  xv = hb[b*H + (i - 768)];
            else                xv = ctx[b*H + (i - 1536)];
            s += xv * wgw[i];
        }
#pragma unroll
        for (int m = 4; m >= 1; m >>= 1) s += __shfl_xor(s, m, 8);
        if (sl == 0) pgen[b] = sigm(s + wgb[0]);
        return;
    }

    __shared__ float Ets[KT][VT];   // 16 KB, read 16B/lane contiguous = conflict-free
    __shared__ float Hs[KCH][32];   // 16 KB, read wave-uniform = broadcast

    int vt = blockIdx.x / KSPL;
    int ks = blockIdx.x % KSPL;
    int v0 = vt * VT;
    int k0 = ks * KCH;

    // stage the block's h chunk once: [k0,k0+128) x 32b, coalesced f4
    {
        const float4* src = (const float4*)(htr + (size_t)k0*32);
        float4* dst = (float4*)&Hs[0][0];
#pragma unroll
        for (int i = 0; i < 4; i++) dst[t + 256*i] = src[t + 256*i];
    }

    int q  = t & 3;        // staging k-quad
    int vs = t >> 2;       // staging v base [0,64)
    int w  = t >> 6;       // wave -> b octet
    int l  = t & 63;       // lane -> 4 v at v0+4l

    // prefetch phase 0
    float4 pre[4];
#pragma unroll
    for (int a = 0; a < 4; a++){
        int vr = v0 + vs + 64*a; if (vr >= V) vr = V-1;
        pre[a] = *(const float4*)(E + (size_t)vr*H + k0 + 4*q);
    }

    float4 acc[8];
#pragma unroll
    for (int j = 0; j < 8; j++){ acc[j].x=0.f; acc[j].y=0.f; acc[j].z=0.f; acc[j].w=0.f; }

    for (int ph = 0; ph < NPH; ph++){
        __syncthreads();
#pragma unroll
        for (int a = 0; a < 4; a++){
            int vloc = vs + 64*a;
            Ets[4*q+0][vloc] = pre[a].x;
            Ets[4*q+1][vloc] = pre[a].y;
            Ets[4*q+2][vloc] = pre[a].z;
            Ets[4*q+3][vloc] = pre[a].w;
        }
        __syncthreads();
        if (ph + 1 < NPH){
            int kn = k0 + (ph+1)*KT;
#pragma unroll
            for (int a = 0; a < 4; a++){
                int vr = v0 + vs + 64*a; if (vr >= V) vr = V-1;
                pre[a] = *(const float4*)(E + (size_t)vr*H + kn + 4*q);
            }
        }
#pragma unroll
        for (int k = 0; k < KT; k++){
            float4 e4 = *(const float4*)(&Ets[k][4*l]);
            const float* hp = &Hs[ph*KT + k][8*w];
            float4 hA = *(const float4*)(hp);
            float4 hB = *(const float4*)(hp + 4);
            acc[0].x += hA.x*e4.x; acc[0].y += hA.x*e4.y; acc[0].z += hA.x*e4.z; acc[0].w += hA.x*e4.w;
            acc[1].x += hA.y*e4.x; acc[1].y += hA.y*e4.y; acc[1].z += hA.y*e4.z; acc[1].w += hA.y*e4.w;
            acc[2].x += hA.z*e4.x; acc[2].y += hA.z*e4.y; acc[2].z += hA.z*e4.z; acc[2].w += hA.z*e4.w;
            acc[3].x += hA.w*e4.x; acc[3].y += hA.w*e4.y; acc[3].z += hA.w*e4.z; acc[3].w += hA.w*e4.w;
            acc[4].x += hB.x*e4.x; acc[4].y += hB.x*e4.y; acc[4].z += hB.x*e4.z; acc[4].w += hB.x*e4.w;
            acc[5].x += hB.y*e4.x; acc[5].y += hB.y*e4.y; acc[5].z += hB.y*e4.z; acc[5].w += hB.y*e4.w;
            acc[6].x += hB.z*e4.x; acc[6].y += hB.z*e4.y; acc[6].z += hB.z*e4.z; acc[6].w += hB.z*e4.w;
            acc[7].x += hB.w*e4.x; acc[7].y += hB.w*e4.y; acc[7].z += hB.w*e4.z; acc[7].w += hB.w*e4.w;
        }
    }
    float* pp = part + (size_t)ks*32*VP;
    int v = v0 + 4*l;   // VP-padded: no store guard needed
#pragma unroll
    for (int j = 0; j < 8; j++){
        int b = 8*w + j;
        *(float4*)(pp + (size_t)b*VP + v) = acc[j];
    }
}

// ---- vred1: sum 6 partials -> lsum, per-(b,chunk) max & expsum (256 blocks) ---
#define VCH 3816   // ceil(V/8)
__global__ __launch_bounds__(256) void vred1_kernel(
    const float* __restrict__ part, float* __restrict__ lsum,
    float* __restrict__ pm, float* __restrict__ ps)
{
    __shared__ float red[256];
    int b = blockIdx.x >> 3, c = blockIdx.x & 7;
    int t = threadIdx.x;
    int vlo = c*VCH;
    int vhi = vlo + VCH; if (vhi > V) vhi = V;

    float r[15]; int n = 0;
    float mx = -INFINITY;
    for (int v = vlo + t; v < vhi; v += 256){
        float x = 0.f;
#pragma unroll
        for (int s = 0; s < KSPL; s++) x += part[(size_t)(32*s + b)*VP + v];
        lsum[(size_t)b*VP + v] = x;
        r[n++] = x;
        mx = fmaxf(mx, x);
    }
    red[t] = mx; __syncthreads();
    for (int s = 128; s > 0; s >>= 1){ if (t < s) red[t] = fmaxf(red[t], red[t+s]); __syncthreads(); }
    mx = red[0]; __syncthreads();
    float sm = 0.f;
    for (int i = 0; i < n; i++) sm += expf(r[i] - mx);
    red[t] = sm; __syncthreads();
    for (int s = 128; s > 0; s >>= 1){ if (t < s) red[t] += red[t+s]; __syncthreads(); }
    if (t == 0){ pm[b*8 + c] = mx; ps[b*8 + c] = red[0]; }
}

// ---- final: softmax*pgen write + in-range pointer scatter (960 blocks) --------
__global__ __launch_bounds__(256) void final_kernel(
    const float* __restrict__ lsum, const float* __restrict__ pm,
    const float* __restrict__ ps, const float* __restrict__ pgen,
    const float* __restrict__ attnH, const int* __restrict__ ids,
    float* __restrict__ out, int u, int mm)
{
    int b = blockIdx.x / 30;
    int c = blockIdx.x % 30;
    int t = threadIdx.x;

    float M = -INFINITY;
#pragma unroll
    for (int i = 0; i < 8; i++) M = fmaxf(M, pm[b*8+i]);
    float Ssum = 0.f;
#pragma unroll
    for (int i = 0; i < 8; i++) Ssum += ps[b*8+i] * expf(pm[b*8+i] - M);
    float pg  = pgen[b];
    float scl = pg / Ssum;

    int vlo = c*1024;
    float* orow = out + (((size_t)b*NU + u)*MV + mm)*(size_t)V;
    int v = vlo + 4*t;
    float4 x = *(const float4*)(lsum + (size_t)b*VP + v);
    if (v + 3 < V){
        float4 o;
        o.x = expf(x.x - M)*scl; o.y = expf(x.y - M)*scl;
        o.z = expf(x.z - M)*scl; o.w = expf(x.w - M)*scl;
        *(float4*)(orow + v) = o;
    } else {
        if (v+0 < V) orow[v+0] = expf(x.x - M)*scl;
        if (v+1 < V) orow[v+1] = expf(x.y - M)*scl;
        if (v+2 < V) orow[v+2] = expf(x.z - M)*scl;
        if (v+3 < V) orow[v+3] = expf(x.w - M)*scl;
    }
    __threadfence();
    __syncthreads();
    // scatter ids that fall in this block's v-range (t indexes s, S==256)
    int id = ids[b*S + t];
    if (id >= vlo && id < vlo + 1024){
        atomicAdd(orow + id, (1.0f - pg) * attnH[b*S + t]);
    }
}

// ---------------- argmax (numpy first-index) + gather next w -------------------
__global__ __launch_bounds__(1024) void argmax_kernel(
    const float* __restrict__ out, int u, int mm,
    const float* __restrict__ E, float* __restrict__ wbuf)
{
    __shared__ float rv[1024];
    __shared__ int   ri[1024];
    int b = blockIdx.x, t = threadIdx.x;
    const float* row = out + (((size_t)b*NU + u)*MV + mm)*(size_t)V;
    float bv = -INFINITY; int bi = 0;
    for (int i = t; i < V; i += 1024){
        float x = row[i];
        if (x > bv){ bv = x; bi = i; }
    }
    rv[t] = bv; ri[t] = bi; __syncthreads();
    for (int s = 512; s > 0; s >>= 1){
        if (t < s){
            if (rv[t+s] > rv[t] || (rv[t+s] == rv[t] && ri[t+s] < ri[t])){
                rv[t] = rv[t+s]; ri[t] = ri[t+s];
            }
        }
        __syncthreads();
    }
    int idx = ri[0];
    for (int k = t; k < H; k += 1024) wbuf[b*H + k] = E[(size_t)idx*H + k];
}

extern "C" void kernel_launch(void* const* d_in, const int* in_sizes, int n_in,
                              void* d_out, int out_size, void* d_ws, size_t ws_size,
                              hipStream_t stream)
{
    const int*   ids = (const int*)  d_in[0];
    const float* dec = (const float*)d_in[1];
    const float* enc = (const float*)d_in[2];
    const float* hid = (const float*)d_in[3];
    const float* E   = (const float*)d_in[4];
    const float* Wih = (const float*)d_in[5];
    const float* Whh = (const float*)d_in[6];
    const float* bih = (const float*)d_in[7];
    const float* bhh = (const float*)d_in[8];
    const float* wgw = (const float*)d_in[9];
    const float* wgb = (const float*)d_in[10];
    float* out = (float*)d_out;
    float* ws  = (float*)d_ws;

    float* wbuf    = ws;                  // 24576
    float* hb0     = ws + 24576;          // 24576
    float* hb1     = ws + 49152;          // 24576
    float* ctxb    = ws + 73728;          // 24576
    float* attnE   = ws + 98304;          // 8192
    float* attnH   = ws + 106496;         // 8192
    float* htr     = ws + 114688;         // 24576
    float* pgenb   = ws + 139264;         // 32
    float* pm      = ws + 139296;         // 256
    float* psb     = ws + 139552;         // 256
    float* lsum    = ws + 139808;         // 32*30720 = 983040
    float* part    = ws + 1122848;        // 6*32*30720 = 5898240  (total ~28.1 MB)

    for (int u = 0; u < NU; u++){
        for (int mm = 0; mm < MV; mm++){
            int st = u*MV + mm;
            const float* wp; int wstride;
            if (mm == 0){ wp = dec + (size_t)u*H; wstride = NU*H; }
            else        { wp = wbuf;              wstride = H; }
            const float* hin = (st == 0) ? hid : ((st & 1) ? hb0 : hb1);
            float*      hout = (st & 1) ? hb1 : hb0;

            gru_kernel<<<768, 256, 0, stream>>>(wp, wstride, hin, hout, htr, Wih, Whh, bih, bhh);
            attn_e_kernel<<<2048, 256, 0, stream>>>(hout, enc, attnE);
            ctx_kernel<<<96, 256, 0, stream>>>(attnE, ids, enc, attnH, ctxb);
            logits_kernel<<<VTILES*KSPL+1, 256, 0, stream>>>(E, htr, part, hout, wp, wstride, ctxb, wgw, wgb, pgenb);
            vred1_kernel<<<256, 256, 0, stream>>>(part, lsum, pm, psb);
            final_kernel<<<960, 256, 0, stream>>>(lsum, pm, psb, pgenb, attnH, ids, out, u, mm);
            if (mm != MV-1)
                argmax_kernel<<<32, 1024, 0, stream>>>(out, u, mm, E, wbuf);
        }
    }
}

// Round 5
// 3640.592 us; speedup vs baseline: 1.3365x; 1.3365x over previous
//
#include <hip/hip_runtime.h>
#include <math.h>

#define B 32
#define S 256
#define H 768
#define V 30522
#define NU 5
#define MV 4
#define NEG_INF -10000.0f

// logits GEMM tiling
#define VP 30720      // padded V stride
#define VT 128        // v per block
#define NVT 239       // ceil(V/VT)
#define KSPL 6
#define KCH 128       // 768/6
#define KT 16         // k per LDS phase
#define NPH (KCH/KT)  // 8 phases
#define VCH 3816      // ceil(V/8) softmax chunk

__device__ __forceinline__ float sigm(float x){ return 1.0f/(1.0f + expf(-x)); }

// ---------------- GRU: h_new = GRUCell(w, h), writes h and h-transposed --------
__global__ __launch_bounds__(256) void gru_kernel(
    const float* __restrict__ wp, int wstride,
    const float* __restrict__ hin, float* __restrict__ hout,
    float* __restrict__ htr,
    const float* __restrict__ Wih, const float* __restrict__ Whh,
    const float* __restrict__ bih, const float* __restrict__ bhh)
{
    int wid  = blockIdx.x * 4 + (threadIdx.x >> 6);
    int lane = threadIdx.x & 63;
    int j  = wid >> 2;
    int bg = wid & 3;

    float aI0[8], aI1[8], aI2[8], aH0[8], aH1[8], aH2[8];
#pragma unroll
    for (int bb = 0; bb < 8; bb++){ aI0[bb]=aI1[bb]=aI2[bb]=aH0[bb]=aH1[bb]=aH2[bb]=0.f; }

#pragma unroll
    for (int it = 0; it < 3; it++){
        int k = it*256 + lane*4;
        float4 w0 = *(const float4*)(Wih + (size_t)(0*H + j)*H + k);
        float4 w1 = *(const float4*)(Wih + (size_t)(1*H + j)*H + k);
        float4 w2 = *(const float4*)(Wih + (size_t)(2*H + j)*H + k);
        float4 u0 = *(const float4*)(Whh + (size_t)(0*H + j)*H + k);
        float4 u1 = *(const float4*)(Whh + (size_t)(1*H + j)*H + k);
        float4 u2 = *(const float4*)(Whh + (size_t)(2*H + j)*H + k);
#pragma unroll
        for (int bb = 0; bb < 8; bb++){
            int b = bg*8 + bb;
            float4 x = *(const float4*)(wp  + (size_t)b*wstride + k);
            float4 h = *(const float4*)(hin + (size_t)b*H + k);
            aI0[bb] += w0.x*x.x + w0.y*x.y + w0.z*x.z + w0.w*x.w;
            aI1[bb] += w1.x*x.x + w1.y*x.y + w1.z*x.z + w1.w*x.w;
            aI2[bb] += w2.x*x.x + w2.y*x.y + w2.z*x.z + w2.w*x.w;
            aH0[bb] += u0.x*h.x + u0.y*h.y + u0.z*h.z + u0.w*h.w;
            aH1[bb] += u1.x*h.x + u1.y*h.y + u1.z*h.z + u1.w*h.w;
            aH2[bb] += u2.x*h.x + u2.y*h.y + u2.z*h.z + u2.w*h.w;
        }
    }
    float rRZ0[8], rRZ1[8], rIN[8], rHN[8];
#pragma unroll
    for (int bb = 0; bb < 8; bb++){
        rRZ0[bb] = aI0[bb] + aH0[bb];
        rRZ1[bb] = aI1[bb] + aH1[bb];
        rIN[bb]  = aI2[bb];
        rHN[bb]  = aH2[bb];
    }
#pragma unroll
    for (int bb = 0; bb < 8; bb++){
#pragma unroll
        for (int m = 32; m >= 1; m >>= 1){
            rRZ0[bb] += __shfl_xor(rRZ0[bb], m, 64);
            rRZ1[bb] += __shfl_xor(rRZ1[bb], m, 64);
            rIN[bb]  += __shfl_xor(rIN[bb],  m, 64);
            rHN[bb]  += __shfl_xor(rHN[bb],  m, 64);
        }
    }
    if (lane == 0){
        float brz0 = bih[j]     + bhh[j];
        float brz1 = bih[H+j]   + bhh[H+j];
        float bin_ = bih[2*H+j];
        float bhn_ = bhh[2*H+j];
#pragma unroll
        for (int bb = 0; bb < 8; bb++){
            int b = bg*8 + bb;
            float r = sigm(rRZ0[bb] + brz0);
            float z = sigm(rRZ1[bb] + brz1);
            float n = tanhf(rIN[bb] + bin_ + r*(rHN[bb] + bhn_));
            float ho = hin[(size_t)b*H + j];
            float hv = (1.0f - z)*n + z*ho;
            hout[(size_t)b*H + j] = hv;
            htr[(size_t)j*32 + b] = hv;
        }
    }
}

// ---------------- attn_e[b,s] = enc[b,s,:] . h[b,:] ----------------------------
__global__ __launch_bounds__(256) void attn_e_kernel(
    const float* __restrict__ hb, const float* __restrict__ enc,
    float* __restrict__ attnE)
{
    int wid  = blockIdx.x * 4 + (threadIdx.x >> 6);
    int lane = threadIdx.x & 63;
    int b = wid >> 8;
    int s = wid & 255;
    const float* er = enc + ((size_t)b*S + s)*H;
    const float* hr = hb + (size_t)b*H;
    float acc = 0.f;
#pragma unroll
    for (int it = 0; it < 3; it++){
        int k = it*256 + lane*4;
        float4 e4 = *(const float4*)(er + k);
        float4 h4 = *(const float4*)(hr + k);
        acc += e4.x*h4.x + e4.y*h4.y + e4.z*h4.z + e4.w*h4.w;
    }
#pragma unroll
    for (int m = 32; m >= 1; m >>= 1) acc += __shfl_xor(acc, m, 64);
    if (lane == 0) attnE[b*S + s] = acc;
}

// ------- masked softmax over S (redundant per k-chunk) + context chunk ---------
__global__ __launch_bounds__(256) void ctx_kernel(
    const float* __restrict__ attnE, const int* __restrict__ ids,
    const float* __restrict__ enc, float* __restrict__ attnH,
    float* __restrict__ ctx)
{
    __shared__ float ah[S];
    __shared__ float red[S];
    int b  = blockIdx.x / 3;
    int kc = blockIdx.x % 3;
    int t  = threadIdx.x;

    float e = attnE[b*S + t];
    if (ids[b*S + t] == 0) e = NEG_INF;
    red[t] = e; __syncthreads();
    for (int s = 128; s > 0; s >>= 1){ if (t < s) red[t] = fmaxf(red[t], red[t+s]); __syncthreads(); }
    float mx = red[0]; __syncthreads();
    float p = expf(e - mx);
    red[t] = p; __syncthreads();
    for (int s = 128; s > 0; s >>= 1){ if (t < s) red[t] += red[t+s]; __syncthreads(); }
    float a = p / red[0];
    ah[t] = a;
    if (kc == 0) attnH[b*S + t] = a;
    __syncthreads();

    int k = kc*256 + t;
    const float* ep = enc + (size_t)b*S*H + k;
    float acc = 0.f;
#pragma unroll 4
    for (int s = 0; s < S; s++) acc += ah[s] * ep[(size_t)s*H];
    ctx[b*H + k] = acc;
}

// ---------------- logits partial GEMM: 128v x 32b tile, K/6 per block ----------
// grid NVT*KSPL = 1434 blocks. Compact body (unroll 1 on phase loop) to fit I$.
__global__ __launch_bounds__(256) void logits_kernel(
    const float* __restrict__ E, const float* __restrict__ htr,
    float* __restrict__ part)
{
    __shared__ float Ets[KT][VT];   // 8 KB
    __shared__ float Hs[KCH][32];   // 16 KB

    int t = threadIdx.x;
    int vt = blockIdx.x / KSPL;
    int ks = blockIdx.x % KSPL;
    int v0 = vt * VT;
    int k0 = ks * KCH;

    // stage the block's h chunk once: [k0,k0+128) x 32b, coalesced f4
    {
        const float4* src = (const float4*)(htr + (size_t)k0*32);
        float4* dst = (float4*)&Hs[0][0];
#pragma unroll
        for (int i = 0; i < 4; i++) dst[t + 256*i] = src[t + 256*i];
    }

    int q  = t & 3;        // staging k-quad
    int vs = t >> 2;       // staging v base [0,64)
    int w  = t >> 6;       // wave -> b octet
    int l  = t & 63;       // lane -> 2 v at v0+2l

    // prefetch phase 0
    float4 pre0, pre1;
    {
        int r0 = v0 + vs;      if (r0 >= V) r0 = V-1;
        int r1 = v0 + vs + 64; if (r1 >= V) r1 = V-1;
        pre0 = *(const float4*)(E + (size_t)r0*H + k0 + 4*q);
        pre1 = *(const float4*)(E + (size_t)r1*H + k0 + 4*q);
    }

    float2 acc[8];
#pragma unroll
    for (int j = 0; j < 8; j++){ acc[j].x = 0.f; acc[j].y = 0.f; }

#pragma unroll 1
    for (int ph = 0; ph < NPH; ph++){
        __syncthreads();
        Ets[4*q+0][vs]    = pre0.x;
        Ets[4*q+1][vs]    = pre0.y;
        Ets[4*q+2][vs]    = pre0.z;
        Ets[4*q+3][vs]    = pre0.w;
        Ets[4*q+0][vs+64] = pre1.x;
        Ets[4*q+1][vs+64] = pre1.y;
        Ets[4*q+2][vs+64] = pre1.z;
        Ets[4*q+3][vs+64] = pre1.w;
        __syncthreads();
        if (ph + 1 < NPH){
            int kn = k0 + (ph+1)*KT;
            int r0 = v0 + vs;      if (r0 >= V) r0 = V-1;
            int r1 = v0 + vs + 64; if (r1 >= V) r1 = V-1;
            pre0 = *(const float4*)(E + (size_t)r0*H + kn + 4*q);
            pre1 = *(const float4*)(E + (size_t)r1*H + kn + 4*q);
        }
#pragma unroll
        for (int k = 0; k < KT; k++){
            float2 e2 = *(const float2*)(&Ets[k][2*l]);
            const float* hp = &Hs[ph*KT + k][8*w];
            float4 hA = *(const float4*)(hp);
            float4 hB = *(const float4*)(hp + 4);
            acc[0].x += hA.x*e2.x; acc[0].y += hA.x*e2.y;
            acc[1].x += hA.y*e2.x; acc[1].y += hA.y*e2.y;
            acc[2].x += hA.z*e2.x; acc[2].y += hA.z*e2.y;
            acc[3].x += hA.w*e2.x; acc[3].y += hA.w*e2.y;
            acc[4].x += hB.x*e2.x; acc[4].y += hB.x*e2.y;
            acc[5].x += hB.y*e2.x; acc[5].y += hB.y*e2.y;
            acc[6].x += hB.z*e2.x; acc[6].y += hB.z*e2.y;
            acc[7].x += hB.w*e2.x; acc[7].y += hB.w*e2.y;
        }
    }
    float* pp = part + (size_t)ks*32*VP;
    int v = v0 + 2*l;    // <= 30590 < VP, pad-safe
#pragma unroll
    for (int j = 0; j < 8; j++){
        int b = 8*w + j;
        *(float2*)(pp + (size_t)b*VP + v) = acc[j];
    }
}

// ---- vredF: sum 6 partials -> lsum; per-(b,chunk) max/expsum/first-argmax -----
// grid 257: [0,256) = b*8+c ; block 256 = p_gen.
__global__ __launch_bounds__(256) void vredF_kernel(
    const float* __restrict__ part, float* __restrict__ lsum,
    float* __restrict__ pm, float* __restrict__ ps, int* __restrict__ pidx,
    const float* __restrict__ hb, const float* __restrict__ wp, int wstride,
    const float* __restrict__ ctx, const float* __restrict__ wgw,
    const float* __restrict__ wgb, float* __restrict__ pgen)
{
    int t = threadIdx.x;
    if (blockIdx.x == 256){
        int b = t >> 3, sl = t & 7;
        float s = 0.f;
        for (int i = sl; i < 2304; i += 8){
            float xv;
            if (i < 768)        xv = wp[(size_t)b*wstride + i];
            else if (i < 1536)  xv = hb[b*H + (i - 768)];
            else                xv = ctx[b*H + (i - 1536)];
            s += xv * wgw[i];
        }
#pragma unroll
        for (int m = 4; m >= 1; m >>= 1) s += __shfl_xor(s, m, 8);
        if (sl == 0) pgen[b] = sigm(s + wgb[0]);
        return;
    }

    __shared__ float red[256];
    __shared__ int   ridx[256];
    int b = blockIdx.x >> 3, c = blockIdx.x & 7;
    int vlo = c*VCH;
    int vhi = vlo + VCH; if (vhi > V) vhi = V;

    float r[15]; int n = 0;
    float mx = -INFINITY; int mi = 0;
    for (int v = vlo + t; v < vhi; v += 256){
        float x = 0.f;
#pragma unroll
        for (int s = 0; s < KSPL; s++) x += part[(size_t)(32*s + b)*VP + v];
        lsum[(size_t)b*VP + v] = x;
        r[n++] = x;
        if (x > mx){ mx = x; mi = v; }
    }
    red[t] = mx; ridx[t] = mi; __syncthreads();
    for (int s = 128; s > 0; s >>= 1){
        if (t < s){
            if (red[t+s] > red[t] || (red[t+s] == red[t] && ridx[t+s] < ridx[t])){
                red[t] = red[t+s]; ridx[t] = ridx[t+s];
            }
        }
        __syncthreads();
    }
    mx = red[0];
    if (t == 0){ pm[b*8 + c] = mx; pidx[b*8 + c] = ridx[0]; }
    __syncthreads();
    float sm = 0.f;
    for (int i = 0; i < n; i++) sm += expf(r[i] - mx);
    red[t] = sm; __syncthreads();
    for (int s = 128; s > 0; s >>= 1){ if (t < s) red[t] += red[t+s]; __syncthreads(); }
    if (t == 0) ps[b*8 + c] = red[0];
}

// ---- argmaxF: final-distribution argmax WITHOUT reading out -------------------
// candidates = scattered ids (<=256) + global-logit argmax. 32 blocks x 256.
__global__ __launch_bounds__(256) void argmaxF_kernel(
    const float* __restrict__ lsum, const float* __restrict__ pm,
    const float* __restrict__ ps, const int* __restrict__ pidx,
    const float* __restrict__ pgen, const float* __restrict__ attnH,
    const int* __restrict__ ids, const float* __restrict__ E,
    float* __restrict__ wbuf)
{
    __shared__ int   sid[S];
    __shared__ float sval[S];
    __shared__ float rv[256];
    __shared__ int   ri[256];
    int b = blockIdx.x, t = threadIdx.x;

    int   id = ids[b*S + t];
    float av = attnH[b*S + t];
    sid[t] = id; sval[t] = av; __syncthreads();

    // group-sum of attention mass for this id (repeated ids accumulate)
    float gsum = 0.f;
    for (int s2 = 0; s2 < S; s2++){
        if (sid[s2] == id) gsum += sval[s2];
    }

    // global softmax stats
    float M = -INFINITY;
#pragma unroll
    for (int c = 0; c < 8; c++) M = fmaxf(M, pm[b*8 + c]);
    float Z = 0.f;
#pragma unroll
    for (int c = 0; c < 8; c++) Z += ps[b*8 + c] * expf(pm[b*8 + c] - M);
    int vstar = V;
#pragma unroll
    for (int c = 7; c >= 0; c--) if (pm[b*8 + c] == M) vstar = pidx[b*8 + c];

    float pg = pgen[b];
    // candidate for this thread's id
    float lv  = lsum[(size_t)b*VP + id];
    float val = pg * expf(lv - M) / Z + (1.0f - pg) * gsum;

    rv[t] = val; ri[t] = id; __syncthreads();
    for (int s = 128; s > 0; s >>= 1){
        if (t < s){
            if (rv[t+s] > rv[t] || (rv[t+s] == rv[t] && ri[t+s] < ri[t])){
                rv[t] = rv[t+s]; ri[t] = ri[t+s];
            }
        }
        __syncthreads();
    }
    // fold in the plain (non-scattered) global argmax candidate
    float vsv = pg / Z;           // pg * exp(M - M) / Z
    int widx = ri[0];
    float wval = rv[0];
    if (vsv > wval || (vsv == wval && vstar < widx)) widx = vstar;

    for (int k = t; k < H; k += 256) wbuf[b*H + k] = E[(size_t)widx*H + k];
}

// ---- finalF: softmax*pgen write + in-range pointer scatter (960 blocks) -------
__global__ __launch_bounds__(256) void finalF_kernel(
    const float* __restrict__ lsum, const float* __restrict__ pm,
    const float* __restrict__ ps, const float* __restrict__ pgen,
    const float* __restrict__ attnH, const int* __restrict__ ids,
    float* __restrict__ out, int u, int mm)
{
    int b = blockIdx.x / 30;
    int c = blockIdx.x % 30;
    int t = threadIdx.x;

    float M = -INFINITY;
#pragma unroll
    for (int i = 0; i < 8; i++) M = fmaxf(M, pm[b*8+i]);
    float Ssum = 0.f;
#pragma unroll
    for (int i = 0; i < 8; i++) Ssum += ps[b*8+i] * expf(pm[b*8+i] - M);
    float pg  = pgen[b];
    float scl = pg / Ssum;

    int vlo = c*1024;
    float* orow = out + (((size_t)b*NU + u)*MV + mm)*(size_t)V;
    int v = vlo + 4*t;
    if (v + 3 < V){
        float4 x = *(const float4*)(lsum + (size_t)b*VP + v);
        float4 o;
        o.x = expf(x.x - M)*scl; o.y = expf(x.y - M)*scl;
        o.z = expf(x.z - M)*scl; o.w = expf(x.w - M)*scl;
        *(float4*)(orow + v) = o;
    } else {
#pragma unroll
        for (int j = 0; j < 4; j++){
            if (v + j < V) orow[v+j] = expf(lsum[(size_t)b*VP + v + j] - M)*scl;
        }
    }
    __syncthreads();   // block-level: stores before atomics to same range
    int id = ids[b*S + t];
    if (id >= vlo && id < vlo + 1024){
        atomicAdd(orow + id, (1.0f - pg) * attnH[b*S + t]);
    }
}

extern "C" void kernel_launch(void* const* d_in, const int* in_sizes, int n_in,
                              void* d_out, int out_size, void* d_ws, size_t ws_size,
                              hipStream_t stream)
{
    const int*   ids = (const int*)  d_in[0];
    const float* dec = (const float*)d_in[1];
    const float* enc = (const float*)d_in[2];
    const float* hid = (const float*)d_in[3];
    const float* E   = (const float*)d_in[4];
    const float* Wih = (const float*)d_in[5];
    const float* Whh = (const float*)d_in[6];
    const float* bih = (const float*)d_in[7];
    const float* bhh = (const float*)d_in[8];
    const float* wgw = (const float*)d_in[9];
    const float* wgb = (const float*)d_in[10];
    float* out = (float*)d_out;
    float* ws  = (float*)d_ws;

    float* wbuf    = ws;                  // 24576
    float* hb0     = ws + 24576;          // 24576
    float* hb1     = ws + 49152;          // 24576
    float* ctxb    = ws + 73728;          // 24576
    float* attnE   = ws + 98304;          // 8192
    float* attnH   = ws + 106496;         // 8192
    float* htr     = ws + 114688;         // 24576
    float* pgenb   = ws + 139264;         // 32
    float* pm      = ws + 139296;         // 256
    float* psb     = ws + 139552;         // 256
    int*   pidx    = (int*)(ws + 139808); // 256
    float* lsum    = ws + 140064;         // 32*30720 = 983040
    float* part    = ws + 1123104;        // 6*32*30720 = 5898240  (~28.1 MB total)

    for (int u = 0; u < NU; u++){
        for (int mm = 0; mm < MV; mm++){
            int st = u*MV + mm;
            const float* wp; int wstride;
            if (mm == 0){ wp = dec + (size_t)u*H; wstride = NU*H; }
            else        { wp = wbuf;              wstride = H; }
            const float* hin = (st == 0) ? hid : ((st & 1) ? hb0 : hb1);
            float*      hout = (st & 1) ? hb1 : hb0;

            gru_kernel<<<768, 256, 0, stream>>>(wp, wstride, hin, hout, htr, Wih, Whh, bih, bhh);
            attn_e_kernel<<<2048, 256, 0, stream>>>(hout, enc, attnE);
            ctx_kernel<<<96, 256, 0, stream>>>(attnE, ids, enc, attnH, ctxb);
            logits_kernel<<<NVT*KSPL, 256, 0, stream>>>(E, htr, part);
            vredF_kernel<<<257, 256, 0, stream>>>(part, lsum, pm, psb, pidx,
                                                  hout, wp, wstride, ctxb, wgw, wgb, pgenb);
            if (mm != MV-1)
                argmaxF_kernel<<<32, 256, 0, stream>>>(lsum, pm, psb, pidx, pgenb,
                                                       attnH, ids, E, wbuf);
            finalF_kernel<<<960, 256, 0, stream>>>(lsum, pm, psb, pgenb, attnH, ids, out, u, mm);
        }
    }
}

// Round 6
// 3618.955 us; speedup vs baseline: 1.3445x; 1.0060x over previous
//
#include <hip/hip_runtime.h>
#include <math.h>

#define B 32
#define S 256
#define H 768
#define V 30522
#define NU 5
#define MV 4
#define NEG_INF -10000.0f

// logits GEMM tiling
#define VP 30720      // padded V stride
#define VT 128        // v per block
#define NVT 239       // ceil(V/VT)
#define KSPL 6
#define KCH 128       // 768/6
#define KT 16         // k per LDS phase
#define NPH (KCH/KT)  // 8 phases
// softmax reduction chunking: 15 chunks x 2048 = 30720 (8 iters x 256 thr, static)
#define NCH 15
#define VCH2 2048

__device__ __forceinline__ float sigm(float x){ return 1.0f/(1.0f + expf(-x)); }

// ---------------- GRU: h_new = GRUCell(w, h), writes h and h-transposed --------
__global__ __launch_bounds__(256) void gru_kernel(
    const float* __restrict__ wp, int wstride,
    const float* __restrict__ hin, float* __restrict__ hout,
    float* __restrict__ htr,
    const float* __restrict__ Wih, const float* __restrict__ Whh,
    const float* __restrict__ bih, const float* __restrict__ bhh)
{
    int wid  = blockIdx.x * 4 + (threadIdx.x >> 6);
    int lane = threadIdx.x & 63;
    int j  = wid >> 2;
    int bg = wid & 3;

    float aI0[8], aI1[8], aI2[8], aH0[8], aH1[8], aH2[8];
#pragma unroll
    for (int bb = 0; bb < 8; bb++){ aI0[bb]=aI1[bb]=aI2[bb]=aH0[bb]=aH1[bb]=aH2[bb]=0.f; }

#pragma unroll
    for (int it = 0; it < 3; it++){
        int k = it*256 + lane*4;
        float4 w0 = *(const float4*)(Wih + (size_t)(0*H + j)*H + k);
        float4 w1 = *(const float4*)(Wih + (size_t)(1*H + j)*H + k);
        float4 w2 = *(const float4*)(Wih + (size_t)(2*H + j)*H + k);
        float4 u0 = *(const float4*)(Whh + (size_t)(0*H + j)*H + k);
        float4 u1 = *(const float4*)(Whh + (size_t)(1*H + j)*H + k);
        float4 u2 = *(const float4*)(Whh + (size_t)(2*H + j)*H + k);
#pragma unroll
        for (int bb = 0; bb < 8; bb++){
            int b = bg*8 + bb;
            float4 x = *(const float4*)(wp  + (size_t)b*wstride + k);
            float4 h = *(const float4*)(hin + (size_t)b*H + k);
            aI0[bb] += w0.x*x.x + w0.y*x.y + w0.z*x.z + w0.w*x.w;
            aI1[bb] += w1.x*x.x + w1.y*x.y + w1.z*x.z + w1.w*x.w;
            aI2[bb] += w2.x*x.x + w2.y*x.y + w2.z*x.z + w2.w*x.w;
            aH0[bb] += u0.x*h.x + u0.y*h.y + u0.z*h.z + u0.w*h.w;
            aH1[bb] += u1.x*h.x + u1.y*h.y + u1.z*h.z + u1.w*h.w;
            aH2[bb] += u2.x*h.x + u2.y*h.y + u2.z*h.z + u2.w*h.w;
        }
    }
    float rRZ0[8], rRZ1[8], rIN[8], rHN[8];
#pragma unroll
    for (int bb = 0; bb < 8; bb++){
        rRZ0[bb] = aI0[bb] + aH0[bb];
        rRZ1[bb] = aI1[bb] + aH1[bb];
        rIN[bb]  = aI2[bb];
        rHN[bb]  = aH2[bb];
    }
#pragma unroll
    for (int bb = 0; bb < 8; bb++){
#pragma unroll
        for (int m = 32; m >= 1; m >>= 1){
            rRZ0[bb] += __shfl_xor(rRZ0[bb], m, 64);
            rRZ1[bb] += __shfl_xor(rRZ1[bb], m, 64);
            rIN[bb]  += __shfl_xor(rIN[bb],  m, 64);
            rHN[bb]  += __shfl_xor(rHN[bb],  m, 64);
        }
    }
    if (lane == 0){
        float brz0 = bih[j]     + bhh[j];
        float brz1 = bih[H+j]   + bhh[H+j];
        float bin_ = bih[2*H+j];
        float bhn_ = bhh[2*H+j];
#pragma unroll
        for (int bb = 0; bb < 8; bb++){
            int b = bg*8 + bb;
            float r = sigm(rRZ0[bb] + brz0);
            float z = sigm(rRZ1[bb] + brz1);
            float n = tanhf(rIN[bb] + bin_ + r*(rHN[bb] + bhn_));
            float ho = hin[(size_t)b*H + j];
            float hv = (1.0f - z)*n + z*ho;
            hout[(size_t)b*H + j] = hv;
            htr[(size_t)j*32 + b] = hv;
        }
    }
}

// ---------------- attn_e[b,s] = enc[b,s,:] . h[b,:] ----------------------------
__global__ __launch_bounds__(256) void attn_e_kernel(
    const float* __restrict__ hb, const float* __restrict__ enc,
    float* __restrict__ attnE)
{
    int wid  = blockIdx.x * 4 + (threadIdx.x >> 6);
    int lane = threadIdx.x & 63;
    int b = wid >> 8;
    int s = wid & 255;
    const float* er = enc + ((size_t)b*S + s)*H;
    const float* hr = hb + (size_t)b*H;
    float acc = 0.f;
#pragma unroll
    for (int it = 0; it < 3; it++){
        int k = it*256 + lane*4;
        float4 e4 = *(const float4*)(er + k);
        float4 h4 = *(const float4*)(hr + k);
        acc += e4.x*h4.x + e4.y*h4.y + e4.z*h4.z + e4.w*h4.w;
    }
#pragma unroll
    for (int m = 32; m >= 1; m >>= 1) acc += __shfl_xor(acc, m, 64);
    if (lane == 0) attnE[b*S + s] = acc;
}

// ------- masked softmax over S (redundant per k-chunk) + context chunk ---------
__global__ __launch_bounds__(256) void ctx_kernel(
    const float* __restrict__ attnE, const int* __restrict__ ids,
    const float* __restrict__ enc, float* __restrict__ attnH,
    float* __restrict__ ctx)
{
    __shared__ float ah[S];
    __shared__ float red[S];
    int b  = blockIdx.x / 3;
    int kc = blockIdx.x % 3;
    int t  = threadIdx.x;

    float e = attnE[b*S + t];
    if (ids[b*S + t] == 0) e = NEG_INF;
    red[t] = e; __syncthreads();
    for (int s = 128; s > 0; s >>= 1){ if (t < s) red[t] = fmaxf(red[t], red[t+s]); __syncthreads(); }
    float mx = red[0]; __syncthreads();
    float p = expf(e - mx);
    red[t] = p; __syncthreads();
    for (int s = 128; s > 0; s >>= 1){ if (t < s) red[t] += red[t+s]; __syncthreads(); }
    float a = p / red[0];
    ah[t] = a;
    if (kc == 0) attnH[b*S + t] = a;
    __syncthreads();

    int k = kc*256 + t;
    const float* ep = enc + (size_t)b*S*H + k;
    float acc = 0.f;
#pragma unroll 4
    for (int s = 0; s < S; s++) acc += ah[s] * ep[(size_t)s*H];
    ctx[b*H + k] = acc;
}

// ---------------- logits partial GEMM: 128v x 32b tile, K/6 per block ----------
__global__ __launch_bounds__(256) void logits_kernel(
    const float* __restrict__ E, const float* __restrict__ htr,
    float* __restrict__ part)
{
    __shared__ float Ets[KT][VT];   // 8 KB
    __shared__ float Hs[KCH][32];   // 16 KB

    int t = threadIdx.x;
    int vt = blockIdx.x / KSPL;
    int ks = blockIdx.x % KSPL;
    int v0 = vt * VT;
    int k0 = ks * KCH;

    {
        const float4* src = (const float4*)(htr + (size_t)k0*32);
        float4* dst = (float4*)&Hs[0][0];
#pragma unroll
        for (int i = 0; i < 4; i++) dst[t + 256*i] = src[t + 256*i];
    }

    int q  = t & 3;
    int vs = t >> 2;
    int w  = t >> 6;
    int l  = t & 63;

    float4 pre0, pre1;
    {
        int r0 = v0 + vs;      if (r0 >= V) r0 = V-1;
        int r1 = v0 + vs + 64; if (r1 >= V) r1 = V-1;
        pre0 = *(const float4*)(E + (size_t)r0*H + k0 + 4*q);
        pre1 = *(const float4*)(E + (size_t)r1*H + k0 + 4*q);
    }

    float2 acc[8];
#pragma unroll
    for (int j = 0; j < 8; j++){ acc[j].x = 0.f; acc[j].y = 0.f; }

#pragma unroll 1
    for (int ph = 0; ph < NPH; ph++){
        __syncthreads();
        Ets[4*q+0][vs]    = pre0.x;
        Ets[4*q+1][vs]    = pre0.y;
        Ets[4*q+2][vs]    = pre0.z;
        Ets[4*q+3][vs]    = pre0.w;
        Ets[4*q+0][vs+64] = pre1.x;
        Ets[4*q+1][vs+64] = pre1.y;
        Ets[4*q+2][vs+64] = pre1.z;
        Ets[4*q+3][vs+64] = pre1.w;
        __syncthreads();
        if (ph + 1 < NPH){
            int kn = k0 + (ph+1)*KT;
            int r0 = v0 + vs;      if (r0 >= V) r0 = V-1;
            int r1 = v0 + vs + 64; if (r1 >= V) r1 = V-1;
            pre0 = *(const float4*)(E + (size_t)r0*H + kn + 4*q);
            pre1 = *(const float4*)(E + (size_t)r1*H + kn + 4*q);
        }
#pragma unroll
        for (int k = 0; k < KT; k++){
            float2 e2 = *(const float2*)(&Ets[k][2*l]);
            const float* hp = &Hs[ph*KT + k][8*w];
            float4 hA = *(const float4*)(hp);
            float4 hB = *(const float4*)(hp + 4);
            acc[0].x += hA.x*e2.x; acc[0].y += hA.x*e2.y;
            acc[1].x += hA.y*e2.x; acc[1].y += hA.y*e2.y;
            acc[2].x += hA.z*e2.x; acc[2].y += hA.z*e2.y;
            acc[3].x += hA.w*e2.x; acc[3].y += hA.w*e2.y;
            acc[4].x += hB.x*e2.x; acc[4].y += hB.x*e2.y;
            acc[5].x += hB.y*e2.x; acc[5].y += hB.y*e2.y;
            acc[6].x += hB.z*e2.x; acc[6].y += hB.z*e2.y;
            acc[7].x += hB.w*e2.x; acc[7].y += hB.w*e2.y;
        }
    }
    float* pp = part + (size_t)ks*32*VP;
    int v = v0 + 2*l;
#pragma unroll
    for (int j = 0; j < 8; j++){
        int b = 8*w + j;
        *(float2*)(pp + (size_t)b*VP + v) = acc[j];
    }
}

// ---- vredF: sum 6 partials -> lsum; per-(b,chunk) max/expsum/first-argmax -----
// grid 481: [0,480) = b*NCH+c ; block 480 = p_gen. Static 8-iteration unroll:
// r[8] stays in VGPRs (round-5 version spilled a 15-entry dynamic array to scratch).
__global__ __launch_bounds__(256) void vredF_kernel(
    const float* __restrict__ part, float* __restrict__ lsum,
    float* __restrict__ pm, float* __restrict__ ps, int* __restrict__ pidx,
    const float* __restrict__ hb, const float* __restrict__ wp, int wstride,
    const float* __restrict__ ctx, const float* __restrict__ wgw,
    const float* __restrict__ wgb, float* __restrict__ pgen)
{
    int t = threadIdx.x;
    if (blockIdx.x == 32*NCH){
        int b = t >> 3, sl = t & 7;
        float s = 0.f;
        for (int i = sl; i < 2304; i += 8){
            float xv;
            if (i < 768)        xv = wp[(size_t)b*wstride + i];
            else if (i < 1536)  xv = hb[b*H + (i - 768)];
            else                xv = ctx[b*H + (i - 1536)];
            s += xv * wgw[i];
        }
#pragma unroll
        for (int m = 4; m >= 1; m >>= 1) s += __shfl_xor(s, m, 8);
        if (sl == 0) pgen[b] = sigm(s + wgb[0]);
        return;
    }

    __shared__ float red[256];
    __shared__ int   ridx[256];
    int b = blockIdx.x / NCH, c = blockIdx.x % NCH;
    int vlo = c*VCH2;

    float r[8];
    float mx = -INFINITY; int mi = 0;
#pragma unroll
    for (int i = 0; i < 8; i++){
        int v = vlo + t + 256*i;
        float x = -INFINITY;
        if (v < V){
            x = part[(size_t)b*VP + v];
#pragma unroll
            for (int s = 1; s < KSPL; s++) x += part[(size_t)(32*s + b)*VP + v];
            lsum[(size_t)b*VP + v] = x;
        }
        r[i] = x;
        if (x > mx){ mx = x; mi = v; }
    }
    red[t] = mx; ridx[t] = mi; __syncthreads();
    for (int s = 128; s > 0; s >>= 1){
        if (t < s){
            if (red[t+s] > red[t] || (red[t+s] == red[t] && ridx[t+s] < ridx[t])){
                red[t] = red[t+s]; ridx[t] = ridx[t+s];
            }
        }
        __syncthreads();
    }
    mx = red[0];
    if (t == 0){ pm[b*NCH + c] = mx; pidx[b*NCH + c] = ridx[0]; }
    __syncthreads();
    float sm = 0.f;
#pragma unroll
    for (int i = 0; i < 8; i++){
        if (vlo + t + 256*i < V) sm += expf(r[i] - mx);
    }
    red[t] = sm; __syncthreads();
    for (int s = 128; s > 0; s >>= 1){ if (t < s) red[t] += red[t+s]; __syncthreads(); }
    if (t == 0) ps[b*NCH + c] = red[0];
}

// ---- argmaxF: final-distribution argmax WITHOUT reading out -------------------
__global__ __launch_bounds__(256) void argmaxF_kernel(
    const float* __restrict__ lsum, const float* __restrict__ pm,
    const float* __restrict__ ps, const int* __restrict__ pidx,
    const float* __restrict__ pgen, const float* __restrict__ attnH,
    const int* __restrict__ ids, const float* __restrict__ E,
    float* __restrict__ wbuf)
{
    __shared__ int   sid[S];
    __shared__ float sval[S];
    __shared__ float rv[256];
    __shared__ int   ri[256];
    int b = blockIdx.x, t = threadIdx.x;

    int   id = ids[b*S + t];
    float av = attnH[b*S + t];
    sid[t] = id; sval[t] = av; __syncthreads();

    float gsum = 0.f;
    for (int s2 = 0; s2 < S; s2++){
        if (sid[s2] == id) gsum += sval[s2];
    }

    float M = -INFINITY;
#pragma unroll
    for (int c = 0; c < NCH; c++) M = fmaxf(M, pm[b*NCH + c]);
    float Z = 0.f;
#pragma unroll
    for (int c = 0; c < NCH; c++) Z += ps[b*NCH + c] * expf(pm[b*NCH + c] - M);
    int vstar = V;
#pragma unroll
    for (int c = NCH-1; c >= 0; c--) if (pm[b*NCH + c] == M) vstar = pidx[b*NCH + c];

    float pg = pgen[b];
    float lv  = lsum[(size_t)b*VP + id];
    float val = pg * expf(lv - M) / Z + (1.0f - pg) * gsum;

    rv[t] = val; ri[t] = id; __syncthreads();
    for (int s = 128; s > 0; s >>= 1){
        if (t < s){
            if (rv[t+s] > rv[t] || (rv[t+s] == rv[t] && ri[t+s] < ri[t])){
                rv[t] = rv[t+s]; ri[t] = ri[t+s];
            }
        }
        __syncthreads();
    }
    float vsv = pg / Z;
    int widx = ri[0];
    float wval = rv[0];
    if (vsv > wval || (vsv == wval && vstar < widx)) widx = vstar;

    for (int k = t; k < H; k += 256) wbuf[b*H + k] = E[(size_t)widx*H + k];
}

// ---- finalF: softmax*pgen write + in-range pointer scatter (960 blocks) -------
__global__ __launch_bounds__(256) void finalF_kernel(
    const float* __restrict__ lsum, const float* __restrict__ pm,
    const float* __restrict__ ps, const float* __restrict__ pgen,
    const float* __restrict__ attnH, const int* __restrict__ ids,
    float* __restrict__ out, int u, int mm)
{
    int b = blockIdx.x / 30;
    int c = blockIdx.x % 30;
    int t = threadIdx.x;

    float M = -INFINITY;
#pragma unroll
    for (int i = 0; i < NCH; i++) M = fmaxf(M, pm[b*NCH+i]);
    float Ssum = 0.f;
#pragma unroll
    for (int i = 0; i < NCH; i++) Ssum += ps[b*NCH+i] * expf(pm[b*NCH+i] - M);
    float pg  = pgen[b];
    float scl = pg / Ssum;

    int vlo = c*1024;
    float* orow = out + (((size_t)b*NU + u)*MV + mm)*(size_t)V;
    int v = vlo + 4*t;
    if (v + 3 < V){
        float4 x = *(const float4*)(lsum + (size_t)b*VP + v);
        float4 o;
        o.x = expf(x.x - M)*scl; o.y = expf(x.y - M)*scl;
        o.z = expf(x.z - M)*scl; o.w = expf(x.w - M)*scl;
        *(float4*)(orow + v) = o;
    } else {
#pragma unroll
        for (int j = 0; j < 4; j++){
            if (v + j < V) orow[v+j] = expf(lsum[(size_t)b*VP + v + j] - M)*scl;
        }
    }
    __syncthreads();
    int id = ids[b*S + t];
    if (id >= vlo && id < vlo + 1024){
        atomicAdd(orow + id, (1.0f - pg) * attnH[b*S + t]);
    }
}

extern "C" void kernel_launch(void* const* d_in, const int* in_sizes, int n_in,
                              void* d_out, int out_size, void* d_ws, size_t ws_size,
                              hipStream_t stream)
{
    const int*   ids = (const int*)  d_in[0];
    const float* dec = (const float*)d_in[1];
    const float* enc = (const float*)d_in[2];
    const float* hid = (const float*)d_in[3];
    const float* E   = (const float*)d_in[4];
    const float* Wih = (const float*)d_in[5];
    const float* Whh = (const float*)d_in[6];
    const float* bih = (const float*)d_in[7];
    const float* bhh = (const float*)d_in[8];
    const float* wgw = (const float*)d_in[9];
    const float* wgb = (const float*)d_in[10];
    float* out = (float*)d_out;
    float* ws  = (float*)d_ws;

    float* wbuf    = ws;                  // 24576
    float* hb0     = ws + 24576;
    float* hb1     = ws + 49152;
    float* ctxb    = ws + 73728;
    float* attnE   = ws + 98304;
    float* attnH   = ws + 106496;
    float* htr     = ws + 114688;
    float* pgenb   = ws + 139264;         // 32
    float* pm      = ws + 139296;         // 480
    float* psb     = ws + 139776;         // 480
    int*   pidx    = (int*)(ws + 140256); // 480
    float* lsum    = ws + 140736;         // 32*30720
    float* part    = ws + 1123776;        // 6*32*30720 (~28.1 MB total)

    for (int u = 0; u < NU; u++){
        for (int mm = 0; mm < MV; mm++){
            int st = u*MV + mm;
            const float* wp; int wstride;
            if (mm == 0){ wp = dec + (size_t)u*H; wstride = NU*H; }
            else        { wp = wbuf;              wstride = H; }
            const float* hin = (st == 0) ? hid : ((st & 1) ? hb0 : hb1);
            float*      hout = (st & 1) ? hb1 : hb0;

            gru_kernel<<<768, 256, 0, stream>>>(wp, wstride, hin, hout, htr, Wih, Whh, bih, bhh);
            attn_e_kernel<<<2048, 256, 0, stream>>>(hout, enc, attnE);
            ctx_kernel<<<96, 256, 0, stream>>>(attnE, ids, enc, attnH, ctxb);
            logits_kernel<<<NVT*KSPL, 256, 0, stream>>>(E, htr, part);
            vredF_kernel<<<32*NCH+1, 256, 0, stream>>>(part, lsum, pm, psb, pidx,
                                                       hout, wp, wstride, ctxb, wgw, wgb, pgenb);
            if (mm != MV-1)
                argmaxF_kernel<<<32, 256, 0, stream>>>(lsum, pm, psb, pidx, pgenb,
                                                       attnH, ids, E, wbuf);
            finalF_kernel<<<960, 256, 0, stream>>>(lsum, pm, psb, pgenb, attnH, ids, out, u, mm);
        }
    }
}